// Round 20
// baseline (318.502 us; speedup 1.0000x reference)
//
#include <hip/hip_runtime.h>
#include <cstddef>
#include <cstdint>

typedef _Float16 half8 __attribute__((ext_vector_type(8)));
typedef float f32x4 __attribute__((ext_vector_type(4)));
typedef float f32x2 __attribute__((ext_vector_type(2)));
typedef unsigned short ushort_t;
typedef unsigned int uint_t;
typedef ushort_t ushort4v __attribute__((ext_vector_type(4)));
typedef float f32x4v __attribute__((ext_vector_type(4)));

#define INV_LN2 1.4426950408889634f

__device__ __forceinline__ ushort_t f_to_f16(float f) {
  _Float16 h = (_Float16)f;
  union { _Float16 h; ushort_t u; } v; v.h = h; return v.u;
}
__device__ __forceinline__ float f16_to_f(ushort_t u) {
  union { ushort_t u; _Float16 h; } v; v.u = u; return (float)v.h;
}

// ---------------------------------------------------------------------------
// CSR build
// ---------------------------------------------------------------------------
__global__ __launch_bounds__(64) void detect_i64_kernel(const int* __restrict__ ei,
                                                        int* __restrict__ flag) {
  if (threadIdx.x == 0) {
    int is32 = 0;
    for (int i = 1; i < 1001; i += 2) {
      if (ei[i] != 0) { is32 = 1; break; }
    }
    *flag = is32;
  }
}

__device__ __forceinline__ int load_src(const int* ei, int is32, int E, int e) {
  return is32 ? ei[e] : ei[2 * e];
}
__device__ __forceinline__ int load_dst(const int* ei, int is32, int E, int e) {
  return is32 ? ei[E + e] : ei[2 * (E + e)];
}

__global__ __launch_bounds__(256) void deg_kernel(const int* __restrict__ ei,
                                                  const int* __restrict__ flag,
                                                  int E, int N, int* __restrict__ deg) {
  int e = blockIdx.x * 256 + threadIdx.x;
  if (e >= E + N) return;
  int d = (e < E) ? load_dst(ei, *flag, E, e) : (e - E);
  atomicAdd(&deg[d], 1);
}

__global__ __launch_bounds__(256) void scan_blk_kernel(const int* __restrict__ deg,
                                                       int* __restrict__ rowptr,
                                                       int* __restrict__ bsum, int N) {
  __shared__ int buf[256];
  int b = blockIdx.x, t = threadIdx.x, i = b * 256 + t;
  int v = (i < N) ? deg[i] : 0;
  buf[t] = v;
  __syncthreads();
  for (int off = 1; off < 256; off <<= 1) {
    int add = (t >= off) ? buf[t - off] : 0;
    __syncthreads();
    buf[t] += add;
    __syncthreads();
  }
  if (i < N) rowptr[i + 1] = buf[t];
  if (t == 255) bsum[b] = buf[255];
  if (b == 0 && t == 0) rowptr[0] = 0;
}

__global__ __launch_bounds__(256) void scan_top_kernel(int* __restrict__ bsum, int NB) {
  __shared__ int buf[256];
  int t = threadIdx.x;
  int v = (t < NB) ? bsum[t] : 0;
  buf[t] = v;
  __syncthreads();
  for (int off = 1; off < 256; off <<= 1) {
    int add = (t >= off) ? buf[t - off] : 0;
    __syncthreads();
    buf[t] += add;
    __syncthreads();
  }
  if (t < NB) bsum[t] = buf[t];
}

__global__ __launch_bounds__(256) void scan_add_kernel(int* __restrict__ rowptr,
                                                       const int* __restrict__ bsum, int N) {
  int b = blockIdx.x, t = threadIdx.x, i = b * 256 + t;
  if (b > 0 && i < N) rowptr[i + 1] += bsum[b - 1];
}

__global__ __launch_bounds__(256) void fill_kernel(const int* __restrict__ ei,
                                                   const int* __restrict__ flag,
                                                   int E, int N,
                                                   const int* __restrict__ rowptr,
                                                   int* __restrict__ fillc,
                                                   int* __restrict__ colbuf) {
  int e = blockIdx.x * 256 + threadIdx.x;
  if (e >= E + N) return;
  int s, d;
  if (e < E) { int is32 = *flag; s = load_src(ei, is32, E, e); d = load_dst(ei, is32, E, e); }
  else { s = e - E; d = s; }
  int pos = atomicAdd(&fillc[d], 1);
  colbuf[rowptr[d] + pos] = s;
}

// ---------------------------------------------------------------------------
// prep kernels
// ---------------------------------------------------------------------------
__global__ __launch_bounds__(256) void prep_weights_kernel(
    const float* __restrict__ W0, const float* __restrict__ W1,
    const float* __restrict__ W2, const float* __restrict__ Wp,
    ushort_t* __restrict__ wsf0, ushort_t* __restrict__ wsf1,
    ushort_t* __restrict__ wsf2, ushort_t* __restrict__ wpf) {
  int b = blockIdx.x;
  if (b < 768) {
    int L = b >> 8;
    const float* W = (L == 0) ? W0 : (L == 1) ? W1 : W2;
    ushort_t* out = (L == 0) ? wsf0 : (L == 1) ? wsf1 : wsf2;
    int t = (b & 255) * 256 + threadIdx.x;   // 0..65535
    int c16 = t >> 13;
    int r = t & 8191;
    int k8 = r >> 7;
    int rem = r & 127;
    int rl = rem >> 3, kl = rem & 7;
    int col = c16 * 16 + rl;
    int k = k8 * 8 + kl;
    int h = k >> 7, f = k & 127;
    out[t] = f_to_f16(0.25f * W[(size_t)f * 512 + h * 128 + col]);
  } else {
    int t = (b - 768) * 256 + threadIdx.x;   // 0..16383
    int blk = t >> 7, rem = t & 127;
    int c16 = blk >> 4, k8 = blk & 15;
    int cl = rem >> 3, kl = rem & 7;
    int col = c16 * 16 + cl, k = k8 * 8 + kl;
    wpf[t] = f_to_f16(Wp[(size_t)k * 128 + col]);
  }
}

// Ws = (1/ln2) * W-folded attention vectors, two layouts. 96 blocks: L = b/32.
__global__ __launch_bounds__(256) void wsd_all_kernel(
    const float* __restrict__ W0, const float* __restrict__ W1,
    const float* __restrict__ W2,
    const float* __restrict__ as0, const float* __restrict__ as1,
    const float* __restrict__ as2,
    const float* __restrict__ ad0, const float* __restrict__ ad1,
    const float* __restrict__ ad2,
    float* __restrict__ Ws4, float* __restrict__ Wd4,
    float* __restrict__ Wsh, float* __restrict__ Wdh) {
  int b = blockIdx.x;
  int L = b >> 5;
  const float* W = (L == 0) ? W0 : (L == 1) ? W1 : W2;
  const float* a_src = (L == 0) ? as0 : (L == 1) ? as1 : as2;
  const float* a_dst = (L == 0) ? ad0 : (L == 1) ? ad1 : ad2;
  int wave = threadIdx.x >> 6, lane = threadIdx.x & 63;
  int f = (b & 31) * 4 + wave;            // f in [0,128)
  int base = lane * 8;
  float4 w0 = *(const float4*)&W[(size_t)f * 512 + base];
  float4 w1 = *(const float4*)&W[(size_t)f * 512 + base + 4];
  float4 s0 = *(const float4*)&a_src[base];
  float4 s1 = *(const float4*)&a_src[base + 4];
  float4 d0 = *(const float4*)&a_dst[base];
  float4 d1 = *(const float4*)&a_dst[base + 4];
  float ps = w0.x*s0.x + w0.y*s0.y + w0.z*s0.z + w0.w*s0.w
           + w1.x*s1.x + w1.y*s1.y + w1.z*s1.z + w1.w*s1.w;
  float pd = w0.x*d0.x + w0.y*d0.y + w0.z*d0.z + w0.w*d0.w
           + w1.x*d1.x + w1.y*d1.y + w1.z*d1.z + w1.w*d1.w;
#pragma unroll
  for (int off = 1; off <= 8; off <<= 1) {
    ps += __shfl_xor(ps, off);
    pd += __shfl_xor(pd, off);
  }
  if ((lane & 15) == 0) {
    int h = lane >> 4;
    float vs = ps * INV_LN2, vd = pd * INV_LN2;
    Ws4[L * 512 + f * 4 + h] = vs;
    Wd4[L * 512 + f * 4 + h] = vd;
    Wsh[L * 512 + h * 128 + f] = vs;
    Wdh[L * 512 + h * 128 + f] = vd;
  }
}

// x prep: single pass over x computes h16 (fp16) AND layer-0 al.
__global__ __launch_bounds__(256) void x_prep_kernel(const float* __restrict__ x,
                                                     const float* __restrict__ Wsh,
                                                     const float* __restrict__ Wdh,
                                                     ushort_t* __restrict__ h16,
                                                     float* __restrict__ al_src,
                                                     float* __restrict__ al_dst, int N) {
  __shared__ float sWs[512], sWd[512];
  int t = threadIdx.x;
  sWs[t] = Wsh[t]; sWs[t + 256] = Wsh[t + 256];
  sWd[t] = Wdh[t]; sWd[t + 256] = Wdh[t + 256];
  __syncthreads();
  int wave = t >> 6, lane = t & 63;
  int n = blockIdx.x * 4 + wave;
  if (n >= N) return;
  float2 hv = *(const float2*)&x[(size_t)n * 128 + lane * 2];
  uint_t pk = (uint_t)f_to_f16(hv.x) | ((uint_t)f_to_f16(hv.y) << 16);
  *(uint_t*)&h16[(size_t)n * 128 + lane * 2] = pk;
  float p[8];
#pragma unroll
  for (int hh = 0; hh < 4; ++hh) {
    p[hh]     = hv.x * sWs[hh * 128 + 2 * lane] + hv.y * sWs[hh * 128 + 2 * lane + 1];
    p[4 + hh] = hv.x * sWd[hh * 128 + 2 * lane] + hv.y * sWd[hh * 128 + 2 * lane + 1];
  }
#pragma unroll
  for (int off = 32; off; off >>= 1)
#pragma unroll
    for (int i = 0; i < 8; ++i) p[i] += __shfl_xor(p[i], off);
  if (lane == 0) {
#pragma unroll
    for (int hh = 0; hh < 4; ++hh) {
      al_src[n * 4 + hh] = p[hh];
      al_dst[n * 4 + hh] = p[4 + hh];
    }
  }
}

// ---------------------------------------------------------------------------
// aggregation v4: 2 nodes/wave; full 8-edge chunks with ALL-8 gather prefetch
// (one pipelined latency) + chunk-ahead colbuf/al_src prefetch; tail (<8)
// uses the 1-deep path. Quad-specialized logits, chunk rescale, fp16 gather.
// Edge order identical to v3 -> bit-identical results.
// ---------------------------------------------------------------------------
__global__ __launch_bounds__(256) void agg_G_kernel(const ushort_t* __restrict__ h16,
                                                    const float* __restrict__ al_src,
                                                    const float* __restrict__ al_dst,
                                                    const int* __restrict__ rowptr,
                                                    const int* __restrict__ colbuf,
                                                    ushort_t* __restrict__ Gf, int N) {
  int wave = threadIdx.x >> 6, lane = threadIdx.x & 63;
  int hl = lane & 31;
  int half_base = lane & 32;
  int q = hl >> 2, hc = hl & 3;
  int qb = lane & ~3;
  int n = blockIdx.x * 8 + wave * 2 + (lane >> 5);
  bool alive = n < N;
  int beg = 0, d = 0;
  float ald_hc = 0.f;
  if (alive) {
    beg = rowptr[n];
    d = rowptr[n + 1] - beg;
    ald_hc = al_dst[(size_t)n * 4 + hc];
  }
  int dm1 = max(d - 1, 0);
  float m_run = -1e30f;
  f32x2 ss01 = {0.f, 0.f}, ss23 = {0.f, 0.f};
  f32x2 a0a = {0.f,0.f}, a0b = {0.f,0.f};
  f32x2 a1a = {0.f,0.f}, a1b = {0.f,0.f};
  f32x2 a2a = {0.f,0.f}, a2b = {0.f,0.f};
  f32x2 a3a = {0.f,0.f}, a3b = {0.f,0.f};

  // chunk-0 index+logit prefetch
  int sq = colbuf[beg + min(q, dm1)];
  float as = al_src[(size_t)sq * 4 + hc];

  int nfull = d >> 3;
  int c0 = 0;
  for (int ci = 0; ci < nfull; ++ci, c0 += 8) {
    // next chunk's index prefetch (valid: clamped)
    int sq_n = colbuf[beg + min(c0 + 8 + q, dm1)];
    // ---- phase 1 (full chunk: all 8 edges valid) ----
    float e = as + ald_hc;
    e = fmaxf(e, 0.2f * e);
    float mc = e;
    mc = fmaxf(mc, __shfl_xor(mc, 4));
    mc = fmaxf(mc, __shfl_xor(mc, 8));
    mc = fmaxf(mc, __shfl_xor(mc, 16));
    float nm = fmaxf(m_run, mc);
    float fown = exp2f(m_run - nm);
    m_run = nm;
    float w_own = exp2f(e - nm);
    // ---- all-8 value gathers upfront (one pipelined latency) ----
    ushort4v hv[8];
#pragma unroll
    for (int jj = 0; jj < 8; ++jj) {
      int s = __shfl(sq, half_base + jj * 4);
      hv[jj] = *(const ushort4v*)&h16[(size_t)s * 128 + hl * 4];
    }
    // next chunk's logit prefetch (hides under phase 2)
    float as_n = al_src[(size_t)sq_n * 4 + hc];
    // ---- rescale ----
    float f0 = __shfl(fown, qb + 0), f1 = __shfl(fown, qb + 1);
    float f2 = __shfl(fown, qb + 2), f3 = __shfl(fown, qb + 3);
    ss01 *= f32x2{f0, f1}; ss23 *= f32x2{f2, f3};
    f32x2 F0 = {f0, f0}, F1 = {f1, f1}, F2 = {f2, f2}, F3 = {f3, f3};
    a0a *= F0; a0b *= F0; a1a *= F1; a1b *= F1;
    a2a *= F2; a2b *= F2; a3a *= F3; a3b *= F3;
    // ---- phase 2: fully unrolled 8 edges ----
#pragma unroll
    for (int jj = 0; jj < 8; ++jj) {
      int wb = half_base + jj * 4;
      float w0 = __shfl(w_own, wb + 0);
      float w1 = __shfl(w_own, wb + 1);
      float w2 = __shfl(w_own, wb + 2);
      float w3 = __shfl(w_own, wb + 3);
      ss01 += f32x2{w0, w1}; ss23 += f32x2{w2, w3};
      f32x2 v01 = {f16_to_f(hv[jj][0]), f16_to_f(hv[jj][1])};
      f32x2 v23 = {f16_to_f(hv[jj][2]), f16_to_f(hv[jj][3])};
      a0a += f32x2{w0, w0} * v01; a0b += f32x2{w0, w0} * v23;
      a1a += f32x2{w1, w1} * v01; a1b += f32x2{w1, w1} * v23;
      a2a += f32x2{w2, w2} * v01; a2b += f32x2{w2, w2} * v23;
      a3a += f32x2{w3, w3} * v01; a3b += f32x2{w3, w3} * v23;
    }
    sq = sq_n; as = as_n;
  }
  // ---- tail: cn (<8) edges, old 1-deep path ----
  int cn = d - c0;
  if (cn > 0) {
    float e = as + ald_hc;
    e = fmaxf(e, 0.2f * e);
    e = (q < cn) ? e : -1e30f;
    float mc = e;
    mc = fmaxf(mc, __shfl_xor(mc, 4));
    mc = fmaxf(mc, __shfl_xor(mc, 8));
    mc = fmaxf(mc, __shfl_xor(mc, 16));
    float nm = fmaxf(m_run, mc);
    float fown = exp2f(m_run - nm);
    m_run = nm;
    float w_own = (q < cn) ? exp2f(e - nm) : 0.f;
    float f0 = __shfl(fown, qb + 0), f1 = __shfl(fown, qb + 1);
    float f2 = __shfl(fown, qb + 2), f3 = __shfl(fown, qb + 3);
    ss01 *= f32x2{f0, f1}; ss23 *= f32x2{f2, f3};
    f32x2 F0 = {f0, f0}, F1 = {f1, f1}, F2 = {f2, f2}, F3 = {f3, f3};
    a0a *= F0; a0b *= F0; a1a *= F1; a1b *= F1;
    a2a *= F2; a2b *= F2; a3a *= F3; a3b *= F3;
    int s_c = __shfl(sq, half_base);
    ushort4v hv_c = *(const ushort4v*)&h16[(size_t)s_c * 128 + hl * 4];
    for (int jj = 0; jj < cn; ++jj) {
      int s_n = __shfl(sq, half_base + min(jj + 1, cn - 1) * 4);
      ushort4v hv_n = *(const ushort4v*)&h16[(size_t)s_n * 128 + hl * 4];
      int wb = half_base + jj * 4;
      float w0 = __shfl(w_own, wb + 0);
      float w1 = __shfl(w_own, wb + 1);
      float w2 = __shfl(w_own, wb + 2);
      float w3 = __shfl(w_own, wb + 3);
      ss01 += f32x2{w0, w1}; ss23 += f32x2{w2, w3};
      f32x2 v01 = {f16_to_f(hv_c[0]), f16_to_f(hv_c[1])};
      f32x2 v23 = {f16_to_f(hv_c[2]), f16_to_f(hv_c[3])};
      a0a += f32x2{w0, w0} * v01; a0b += f32x2{w0, w0} * v23;
      a1a += f32x2{w1, w1} * v01; a1b += f32x2{w1, w1} * v23;
      a2a += f32x2{w2, w2} * v01; a2b += f32x2{w2, w2} * v23;
      a3a += f32x2{w3, w3} * v01; a3b += f32x2{w3, w3} * v23;
      hv_c = hv_n;
    }
  }
  if (!alive) return;
  float g[4][4];
  float inv;
  inv = 1.f / (ss01.x + 1e-16f);
  g[0][0] = a0a.x * inv; g[0][1] = a0a.y * inv; g[0][2] = a0b.x * inv; g[0][3] = a0b.y * inv;
  inv = 1.f / (ss01.y + 1e-16f);
  g[1][0] = a1a.x * inv; g[1][1] = a1a.y * inv; g[1][2] = a1b.x * inv; g[1][3] = a1b.y * inv;
  inv = 1.f / (ss23.x + 1e-16f);
  g[2][0] = a2a.x * inv; g[2][1] = a2a.y * inv; g[2][2] = a2b.x * inv; g[2][3] = a2b.y * inv;
  inv = 1.f / (ss23.y + 1e-16f);
  g[3][0] = a3a.x * inv; g[3][1] = a3a.y * inv; g[3][2] = a3b.x * inv; g[3][3] = a3b.y * inv;
#pragma unroll
  for (int h = 0; h < 4; ++h) {
    ushort_t q0 = f_to_f16(g[h][0]), q1 = f_to_f16(g[h][1]);
    ushort_t q2 = f_to_f16(g[h][2]), q3 = f_to_f16(g[h][3]);
    size_t o = ((size_t)(n >> 4) * 64 + h * 16 + (hl >> 1)) * 128 + (n & 15) * 8 + (hl & 1) * 4;
    *(uint2*)&Gf[o] = make_uint2((uint_t)q0 | ((uint_t)q1 << 16),
                                 (uint_t)q2 | ((uint_t)q3 << 16));
  }
}

// ---------------------------------------------------------------------------
// Barrier-lean fp16 MFMA GEMM, K-split 2x. A fragments ALL prefetched upfront;
// B (L2-resident) 1-deep prefetched. 4 waves/block. MODE 0: fp16 row out
// (relu) + fused next-layer al; MODE 1: fp16 frag out (relu); MODE 2: fp32.
// ---------------------------------------------------------------------------
template <int K, int MODE>
__global__ __launch_bounds__(256) void gemm_frag_kernel(
    const ushort_t* __restrict__ Af, const ushort_t* __restrict__ Bf,
    ushort_t* __restrict__ H16, ushort_t* __restrict__ Cf16, float* __restrict__ Cf,
    const float* __restrict__ WsN, const float* __restrict__ WdN,
    float* __restrict__ alS, float* __restrict__ alD,
    int M, const float* __restrict__ bias) {
  constexpr int KT = K >> 5;
  constexpr int KTH = KT >> 1;        // kts per wave (K-split 2x)
  constexpr int PS = 16 * K;          // panel stride (ushorts)
  __shared__ float lacc[2][8][4][64]; // 16 KB, lane-stride 4B: conflict-free
  int lane = threadIdx.x & 63;
  int wv = threadIdx.x >> 6;
  int pair = wv >> 1, khalf = wv & 1;
  int wid = blockIdx.x * 2 + pair;
  int krow = lane >> 4, ml = lane & 15;
  int lb = krow * 128 + ml * 8;
  size_t abase = (size_t)wid * PS + lb + (size_t)khalf * KTH * 512;
  size_t bbase = (size_t)lb + (size_t)khalf * KTH * 512;
  f32x4 acc[8] = {};
  half8 a[KTH];
#pragma unroll
  for (int kt = 0; kt < KTH; ++kt)
    a[kt] = *(const half8*)&Af[abase + kt * 512];
  half8 b_c[8];
#pragma unroll
  for (int j = 0; j < 8; ++j) b_c[j] = *(const half8*)&Bf[j * PS + bbase];
#pragma unroll
  for (int kt = 0; kt < KTH; ++kt) {
    half8 b_n[8];
#pragma unroll
    for (int j = 0; j < 8; ++j)
      b_n[j] = (kt + 1 < KTH) ? *(const half8*)&Bf[j * PS + bbase + (kt + 1) * 512]
                              : b_c[j];
#pragma unroll
    for (int j = 0; j < 8; ++j)
      acc[j] = __builtin_amdgcn_mfma_f32_16x16x32_f16(a[kt], b_c[j], acc[j], 0, 0, 0);
#pragma unroll
    for (int j = 0; j < 8; ++j) b_c[j] = b_n[j];
  }
  if (khalf == 1) {
#pragma unroll
    for (int j = 0; j < 8; ++j)
#pragma unroll
      for (int c = 0; c < 4; ++c) lacc[pair][j][c][lane] = acc[j][c];
  }
  __syncthreads();
  if (khalf == 1) return;
#pragma unroll
  for (int j = 0; j < 8; ++j)
#pragma unroll
    for (int c = 0; c < 4; ++c) acc[j][c] += lacc[pair][j][c][lane];

  int wrow0 = wid * 16;
  if (MODE == 0) {
    float ps[4][4] = {};   // [hh][r]
    float pd[4][4] = {};
#pragma unroll
    for (int j = 0; j < 8; ++j) {
      int col = j * 16 + ml;
      float bv = bias[col];
      float4 w4s = *(const float4*)&WsN[col * 4];
      float4 w4d = *(const float4*)&WdN[col * 4];
#pragma unroll
      for (int r = 0; r < 4; ++r) {
        int row = wrow0 + krow * 4 + r;
        float v = fmaxf(acc[j][r] + bv, 0.f);
        if (row < M) H16[(size_t)row * 128 + col] = f_to_f16(v);
        ps[0][r] += v * w4s.x; ps[1][r] += v * w4s.y;
        ps[2][r] += v * w4s.z; ps[3][r] += v * w4s.w;
        pd[0][r] += v * w4d.x; pd[1][r] += v * w4d.y;
        pd[2][r] += v * w4d.z; pd[3][r] += v * w4d.w;
      }
    }
#pragma unroll
    for (int off = 1; off <= 8; off <<= 1) {
#pragma unroll
      for (int hh = 0; hh < 4; ++hh)
#pragma unroll
        for (int r = 0; r < 4; ++r) {
          ps[hh][r] += __shfl_xor(ps[hh][r], off);
          pd[hh][r] += __shfl_xor(pd[hh][r], off);
        }
    }
    if (ml == 0) {
#pragma unroll
      for (int r = 0; r < 4; ++r) {
        int row = wrow0 + krow * 4 + r;
        if (row < M) {
#pragma unroll
          for (int hh = 0; hh < 4; ++hh) {
            alS[row * 4 + hh] = ps[hh][r];
            alD[row * 4 + hh] = pd[hh][r];
          }
        }
      }
    }
  } else {
#pragma unroll
    for (int j = 0; j < 8; ++j) {
      int col = j * 16 + ml;
      float bv = bias[col];
#pragma unroll
      for (int r = 0; r < 4; ++r) {
        int row = wrow0 + krow * 4 + r;
        if (row < M) {
          float v = acc[j][r] + bv;
          if (MODE != 2) v = fmaxf(v, 0.f);
          if (MODE == 1) {
            size_t o = ((size_t)(row >> 4) * 16 + (col >> 3)) * 128 + (row & 15) * 8 + (col & 7);
            Cf16[o] = f_to_f16(v);
          } else {
            Cf[(size_t)row * 128 + col] = v;
          }
        }
      }
    }
  }
}

// ---------------------------------------------------------------------------
extern "C" void kernel_launch(void* const* d_in, const int* in_sizes, int n_in,
                              void* d_out, int out_size, void* d_ws, size_t ws_size,
                              hipStream_t stream) {
  const float* x  = (const float*)d_in[0];
  const int*   ei = (const int*)d_in[1];
  const float* Wl[3]  = {(const float*)d_in[2], (const float*)d_in[6], (const float*)d_in[10]};
  const float* asr[3] = {(const float*)d_in[3], (const float*)d_in[7], (const float*)d_in[11]};
  const float* adr[3] = {(const float*)d_in[4], (const float*)d_in[8], (const float*)d_in[12]};
  const float* bl[3]  = {(const float*)d_in[5], (const float*)d_in[9], (const float*)d_in[13]};
  const float* Wp = (const float*)d_in[14];
  const float* bp = (const float*)d_in[15];

  const int N = in_sizes[0] / 128;   // 50000
  const int E = in_sizes[1] / 2;     // 400000
  const int EN = E + N;
  const int Mtiles = (N + 127) / 128;  // 391
  const int Mp = Mtiles * 128;         // 50048
  const int NB = (N + 255) / 256;
  const int NPB2 = Mp / 16 / 2;        // 1564 GEMM blocks (2 panels x 2 waves)

  char* ws = (char*)d_ws;
  size_t off = 0;
  auto carve = [&](size_t bytes) -> void* {
    void* p = ws + off;
    off = (off + bytes + 255) & ~(size_t)255;
    return p;
  };
  ushort_t* Gf    = (ushort_t*)carve((size_t)Mp * 512 * 2);  // fp16 frag layout
  ushort_t* h16   = (ushort_t*)carve((size_t)N * 128 * 2);   // fp16 h (agg gather)
  ushort_t* h3f   = (ushort_t*)carve((size_t)Mp * 128 * 2);  // fp16 frag (proj input)
  ushort_t* wsf0  = (ushort_t*)carve((size_t)128 * 512 * 2);
  ushort_t* wsf1  = (ushort_t*)carve((size_t)128 * 512 * 2);
  ushort_t* wsf2  = (ushort_t*)carve((size_t)128 * 512 * 2);
  ushort_t* wpf   = (ushort_t*)carve((size_t)128 * 128 * 2);
  float*    alsrc = (float*)carve((size_t)N * 4 * 4);
  float*    aldst = (float*)carve((size_t)N * 4 * 4);
  float*    Ws4   = (float*)carve(3 * 512 * 4);
  float*    Wd4   = (float*)carve(3 * 512 * 4);
  float*    Wsh   = (float*)carve(3 * 512 * 4);
  float*    Wdh   = (float*)carve(3 * 512 * 4);
  int*      rowptr= (int*)carve((size_t)(N + 1) * 4);
  int*      deg   = (int*)carve((size_t)N * 4);
  int*      bsum  = (int*)carve(256 * 4);
  int*      fillc = (int*)carve((size_t)N * 4);
  int*      colbuf= (int*)carve((size_t)EN * 4);
  int*      flag  = (int*)carve(256);

  // ---- CSR build ----
  detect_i64_kernel<<<1, 64, 0, stream>>>(ei, flag);
  hipMemsetAsync(deg, 0, (size_t)N * 4, stream);
  hipMemsetAsync(fillc, 0, (size_t)N * 4, stream);
  int ebl = (EN + 255) / 256;
  deg_kernel<<<ebl, 256, 0, stream>>>(ei, flag, E, N, deg);
  scan_blk_kernel<<<NB, 256, 0, stream>>>(deg, rowptr, bsum, N);
  scan_top_kernel<<<1, 256, 0, stream>>>(bsum, NB);
  scan_add_kernel<<<NB, 256, 0, stream>>>(rowptr, bsum, N);
  fill_kernel<<<ebl, 256, 0, stream>>>(ei, flag, E, N, rowptr, fillc, colbuf);

  // ---- weight prep; single x pass (h16 + layer-0 al) ----
  prep_weights_kernel<<<832, 256, 0, stream>>>(Wl[0], Wl[1], Wl[2], Wp,
                                               wsf0, wsf1, wsf2, wpf);
  wsd_all_kernel<<<96, 256, 0, stream>>>(Wl[0], Wl[1], Wl[2],
                                         asr[0], asr[1], asr[2],
                                         adr[0], adr[1], adr[2],
                                         Ws4, Wd4, Wsh, Wdh);
  x_prep_kernel<<<(N + 3) / 4, 256, 0, stream>>>(x, Wsh, Wdh, h16, alsrc, aldst, N);

  // ---- 3 GAT layers ----
  ushort_t* wsfL[3] = {wsf0, wsf1, wsf2};
  for (int L = 0; L < 3; ++L) {
    agg_G_kernel<<<Mp / 8, 256, 0, stream>>>(h16, alsrc, aldst,
                                             rowptr, colbuf, Gf, N);
    if (L < 2) {
      gemm_frag_kernel<512, 0><<<NPB2, 256, 0, stream>>>(Gf, wsfL[L],
                                                         h16, nullptr, nullptr,
                                                         Ws4 + (L + 1) * 512, Wd4 + (L + 1) * 512,
                                                         alsrc, aldst, N, bl[L]);
    } else {
      gemm_frag_kernel<512, 1><<<NPB2, 256, 0, stream>>>(Gf, wsfL[L],
                                                         nullptr, h3f, nullptr,
                                                         nullptr, nullptr, nullptr, nullptr,
                                                         N, bl[L]);
    }
  }

  // ---- final projection: out = h3 @ Wp + bp ----
  gemm_frag_kernel<128, 2><<<NPB2, 256, 0, stream>>>(h3f, wpf,
                                                     nullptr, nullptr, (float*)d_out,
                                                     nullptr, nullptr, nullptr, nullptr,
                                                     N, bp);
}

// Round 21
// 304.707 us; speedup vs baseline: 1.0453x; 1.0453x over previous
//
#include <hip/hip_runtime.h>
#include <cstddef>
#include <cstdint>

typedef _Float16 half8 __attribute__((ext_vector_type(8)));
typedef float f32x4 __attribute__((ext_vector_type(4)));
typedef float f32x2 __attribute__((ext_vector_type(2)));
typedef unsigned short ushort_t;
typedef unsigned int uint_t;
typedef ushort_t ushort4v __attribute__((ext_vector_type(4)));
typedef float f32x4v __attribute__((ext_vector_type(4)));

#define INV_LN2 1.4426950408889634f

__device__ __forceinline__ ushort_t f_to_f16(float f) {
  _Float16 h = (_Float16)f;
  union { _Float16 h; ushort_t u; } v; v.h = h; return v.u;
}
__device__ __forceinline__ float f16_to_f(ushort_t u) {
  union { ushort_t u; _Float16 h; } v; v.u = u; return (float)v.h;
}

// ---------------------------------------------------------------------------
// CSR build
// ---------------------------------------------------------------------------
__global__ __launch_bounds__(64) void detect_i64_kernel(const int* __restrict__ ei,
                                                        int* __restrict__ flag) {
  if (threadIdx.x == 0) {
    int is32 = 0;
    for (int i = 1; i < 1001; i += 2) {
      if (ei[i] != 0) { is32 = 1; break; }
    }
    *flag = is32;
  }
}

__device__ __forceinline__ int load_src(const int* ei, int is32, int E, int e) {
  return is32 ? ei[e] : ei[2 * e];
}
__device__ __forceinline__ int load_dst(const int* ei, int is32, int E, int e) {
  return is32 ? ei[E + e] : ei[2 * (E + e)];
}

__global__ __launch_bounds__(256) void deg_kernel(const int* __restrict__ ei,
                                                  const int* __restrict__ flag,
                                                  int E, int N, int* __restrict__ deg) {
  int e = blockIdx.x * 256 + threadIdx.x;
  if (e >= E + N) return;
  int d = (e < E) ? load_dst(ei, *flag, E, e) : (e - E);
  atomicAdd(&deg[d], 1);
}

__global__ __launch_bounds__(256) void scan_blk_kernel(const int* __restrict__ deg,
                                                       int* __restrict__ rowptr,
                                                       int* __restrict__ bsum, int N) {
  __shared__ int buf[256];
  int b = blockIdx.x, t = threadIdx.x, i = b * 256 + t;
  int v = (i < N) ? deg[i] : 0;
  buf[t] = v;
  __syncthreads();
  for (int off = 1; off < 256; off <<= 1) {
    int add = (t >= off) ? buf[t - off] : 0;
    __syncthreads();
    buf[t] += add;
    __syncthreads();
  }
  if (i < N) rowptr[i + 1] = buf[t];
  if (t == 255) bsum[b] = buf[255];
  if (b == 0 && t == 0) rowptr[0] = 0;
}

__global__ __launch_bounds__(256) void scan_top_kernel(int* __restrict__ bsum, int NB) {
  __shared__ int buf[256];
  int t = threadIdx.x;
  int v = (t < NB) ? bsum[t] : 0;
  buf[t] = v;
  __syncthreads();
  for (int off = 1; off < 256; off <<= 1) {
    int add = (t >= off) ? buf[t - off] : 0;
    __syncthreads();
    buf[t] += add;
    __syncthreads();
  }
  if (t < NB) bsum[t] = buf[t];
}

__global__ __launch_bounds__(256) void scan_add_kernel(int* __restrict__ rowptr,
                                                       const int* __restrict__ bsum, int N) {
  int b = blockIdx.x, t = threadIdx.x, i = b * 256 + t;
  if (b > 0 && i < N) rowptr[i + 1] += bsum[b - 1];
}

__global__ __launch_bounds__(256) void fill_kernel(const int* __restrict__ ei,
                                                   const int* __restrict__ flag,
                                                   int E, int N,
                                                   const int* __restrict__ rowptr,
                                                   int* __restrict__ fillc,
                                                   int* __restrict__ colbuf) {
  int e = blockIdx.x * 256 + threadIdx.x;
  if (e >= E + N) return;
  int s, d;
  if (e < E) { int is32 = *flag; s = load_src(ei, is32, E, e); d = load_dst(ei, is32, E, e); }
  else { s = e - E; d = s; }
  int pos = atomicAdd(&fillc[d], 1);
  colbuf[rowptr[d] + pos] = s;
}

// ---------------------------------------------------------------------------
// prep kernels
// ---------------------------------------------------------------------------
__global__ __launch_bounds__(256) void prep_weights_kernel(
    const float* __restrict__ W0, const float* __restrict__ W1,
    const float* __restrict__ W2, const float* __restrict__ Wp,
    ushort_t* __restrict__ wsf0, ushort_t* __restrict__ wsf1,
    ushort_t* __restrict__ wsf2, ushort_t* __restrict__ wpf) {
  int b = blockIdx.x;
  if (b < 768) {
    int L = b >> 8;
    const float* W = (L == 0) ? W0 : (L == 1) ? W1 : W2;
    ushort_t* out = (L == 0) ? wsf0 : (L == 1) ? wsf1 : wsf2;
    int t = (b & 255) * 256 + threadIdx.x;   // 0..65535
    int c16 = t >> 13;
    int r = t & 8191;
    int k8 = r >> 7;
    int rem = r & 127;
    int rl = rem >> 3, kl = rem & 7;
    int col = c16 * 16 + rl;
    int k = k8 * 8 + kl;
    int h = k >> 7, f = k & 127;
    out[t] = f_to_f16(0.25f * W[(size_t)f * 512 + h * 128 + col]);
  } else {
    int t = (b - 768) * 256 + threadIdx.x;   // 0..16383
    int blk = t >> 7, rem = t & 127;
    int c16 = blk >> 4, k8 = blk & 15;
    int cl = rem >> 3, kl = rem & 7;
    int col = c16 * 16 + cl, k = k8 * 8 + kl;
    wpf[t] = f_to_f16(Wp[(size_t)k * 128 + col]);
  }
}

// Ws = (1/ln2) * W-folded attention vectors, two layouts. 96 blocks: L = b/32.
__global__ __launch_bounds__(256) void wsd_all_kernel(
    const float* __restrict__ W0, const float* __restrict__ W1,
    const float* __restrict__ W2,
    const float* __restrict__ as0, const float* __restrict__ as1,
    const float* __restrict__ as2,
    const float* __restrict__ ad0, const float* __restrict__ ad1,
    const float* __restrict__ ad2,
    float* __restrict__ Ws4, float* __restrict__ Wd4,
    float* __restrict__ Wsh, float* __restrict__ Wdh) {
  int b = blockIdx.x;
  int L = b >> 5;
  const float* W = (L == 0) ? W0 : (L == 1) ? W1 : W2;
  const float* a_src = (L == 0) ? as0 : (L == 1) ? as1 : as2;
  const float* a_dst = (L == 0) ? ad0 : (L == 1) ? ad1 : ad2;
  int wave = threadIdx.x >> 6, lane = threadIdx.x & 63;
  int f = (b & 31) * 4 + wave;            // f in [0,128)
  int base = lane * 8;
  float4 w0 = *(const float4*)&W[(size_t)f * 512 + base];
  float4 w1 = *(const float4*)&W[(size_t)f * 512 + base + 4];
  float4 s0 = *(const float4*)&a_src[base];
  float4 s1 = *(const float4*)&a_src[base + 4];
  float4 d0 = *(const float4*)&a_dst[base];
  float4 d1 = *(const float4*)&a_dst[base + 4];
  float ps = w0.x*s0.x + w0.y*s0.y + w0.z*s0.z + w0.w*s0.w
           + w1.x*s1.x + w1.y*s1.y + w1.z*s1.z + w1.w*s1.w;
  float pd = w0.x*d0.x + w0.y*d0.y + w0.z*d0.z + w0.w*d0.w
           + w1.x*d1.x + w1.y*d1.y + w1.z*d1.z + w1.w*d1.w;
#pragma unroll
  for (int off = 1; off <= 8; off <<= 1) {
    ps += __shfl_xor(ps, off);
    pd += __shfl_xor(pd, off);
  }
  if ((lane & 15) == 0) {
    int h = lane >> 4;
    float vs = ps * INV_LN2, vd = pd * INV_LN2;
    Ws4[L * 512 + f * 4 + h] = vs;
    Wd4[L * 512 + f * 4 + h] = vd;
    Wsh[L * 512 + h * 128 + f] = vs;
    Wdh[L * 512 + h * 128 + f] = vd;
  }
}

// x prep: single pass over x computes h16 (fp16) AND layer-0 al.
// One wave per node; Ws/Wd in [h][128] layout.
__global__ __launch_bounds__(256) void x_prep_kernel(const float* __restrict__ x,
                                                     const float* __restrict__ Wsh,
                                                     const float* __restrict__ Wdh,
                                                     ushort_t* __restrict__ h16,
                                                     float* __restrict__ al_src,
                                                     float* __restrict__ al_dst, int N) {
  __shared__ float sWs[512], sWd[512];
  int t = threadIdx.x;
  sWs[t] = Wsh[t]; sWs[t + 256] = Wsh[t + 256];
  sWd[t] = Wdh[t]; sWd[t + 256] = Wdh[t + 256];
  __syncthreads();
  int wave = t >> 6, lane = t & 63;
  int n = blockIdx.x * 4 + wave;
  if (n >= N) return;
  float2 hv = *(const float2*)&x[(size_t)n * 128 + lane * 2];
  uint_t pk = (uint_t)f_to_f16(hv.x) | ((uint_t)f_to_f16(hv.y) << 16);
  *(uint_t*)&h16[(size_t)n * 128 + lane * 2] = pk;
  float p[8];
#pragma unroll
  for (int hh = 0; hh < 4; ++hh) {
    p[hh]     = hv.x * sWs[hh * 128 + 2 * lane] + hv.y * sWs[hh * 128 + 2 * lane + 1];
    p[4 + hh] = hv.x * sWd[hh * 128 + 2 * lane] + hv.y * sWd[hh * 128 + 2 * lane + 1];
  }
#pragma unroll
  for (int off = 32; off; off >>= 1)
#pragma unroll
    for (int i = 0; i < 8; ++i) p[i] += __shfl_xor(p[i], off);
  if (lane == 0) {
#pragma unroll
    for (int hh = 0; hh < 4; ++hh) {
      al_src[n * 4 + hh] = p[hh];
      al_dst[n * 4 + hh] = p[4 + hh];
    }
  }
}

// ---------------------------------------------------------------------------
// aggregation v3: 2 nodes/wave, chunks of 8 edges, quad-specialized logits,
// chunk-granularity rescale, shuffled weight broadcast, fp16 gather.
// fp16 frag output.
// ---------------------------------------------------------------------------
__global__ __launch_bounds__(256) void agg_G_kernel(const ushort_t* __restrict__ h16,
                                                    const float* __restrict__ al_src,
                                                    const float* __restrict__ al_dst,
                                                    const int* __restrict__ rowptr,
                                                    const int* __restrict__ colbuf,
                                                    ushort_t* __restrict__ Gf, int N) {
  int wave = threadIdx.x >> 6, lane = threadIdx.x & 63;
  int hl = lane & 31;
  int half_base = lane & 32;
  int q = hl >> 2, hc = hl & 3;
  int qb = lane & ~3;
  int n = blockIdx.x * 8 + wave * 2 + (lane >> 5);
  bool alive = n < N;
  int beg = 0, d = 0;
  float ald_hc = 0.f;
  if (alive) {
    beg = rowptr[n];
    d = rowptr[n + 1] - beg;
    ald_hc = al_dst[(size_t)n * 4 + hc];
  }
  int dm1 = max(d - 1, 0);
  float m_run = -1e30f;
  f32x2 ss01 = {0.f, 0.f}, ss23 = {0.f, 0.f};
  f32x2 a0a = {0.f,0.f}, a0b = {0.f,0.f};
  f32x2 a1a = {0.f,0.f}, a1b = {0.f,0.f};
  f32x2 a2a = {0.f,0.f}, a2b = {0.f,0.f};
  f32x2 a3a = {0.f,0.f}, a3b = {0.f,0.f};

  for (int c0 = 0; c0 < d; c0 += 8) {
    int cn = min(8, d - c0);
    int j = c0 + q;
    int sq = colbuf[beg + min(j, dm1)];
    float e = al_src[(size_t)sq * 4 + hc] + ald_hc;
    e = fmaxf(e, 0.2f * e);
    e = (q < cn) ? e : -1e30f;
    float mc = e;
    mc = fmaxf(mc, __shfl_xor(mc, 4));
    mc = fmaxf(mc, __shfl_xor(mc, 8));
    mc = fmaxf(mc, __shfl_xor(mc, 16));
    float nm = fmaxf(m_run, mc);
    float fown = exp2f(m_run - nm);
    m_run = nm;
    float w_own = (q < cn) ? exp2f(e - nm) : 0.f;
    float f0 = __shfl(fown, qb + 0), f1 = __shfl(fown, qb + 1);
    float f2 = __shfl(fown, qb + 2), f3 = __shfl(fown, qb + 3);
    ss01 *= f32x2{f0, f1}; ss23 *= f32x2{f2, f3};
    f32x2 F0 = {f0, f0}, F1 = {f1, f1}, F2 = {f2, f2}, F3 = {f3, f3};
    a0a *= F0; a0b *= F0; a1a *= F1; a1b *= F1;
    a2a *= F2; a2b *= F2; a3a *= F3; a3b *= F3;
    int s_c = __shfl(sq, half_base);
    ushort4v hv_c = *(const ushort4v*)&h16[(size_t)s_c * 128 + hl * 4];
    for (int jj = 0; jj < cn; ++jj) {
      int s_n = __shfl(sq, half_base + min(jj + 1, cn - 1) * 4);
      ushort4v hv_n = *(const ushort4v*)&h16[(size_t)s_n * 128 + hl * 4];
      int wb = half_base + jj * 4;
      float w0 = __shfl(w_own, wb + 0);
      float w1 = __shfl(w_own, wb + 1);
      float w2 = __shfl(w_own, wb + 2);
      float w3 = __shfl(w_own, wb + 3);
      ss01 += f32x2{w0, w1}; ss23 += f32x2{w2, w3};
      f32x2 v01 = {f16_to_f(hv_c[0]), f16_to_f(hv_c[1])};
      f32x2 v23 = {f16_to_f(hv_c[2]), f16_to_f(hv_c[3])};
      a0a += f32x2{w0, w0} * v01; a0b += f32x2{w0, w0} * v23;
      a1a += f32x2{w1, w1} * v01; a1b += f32x2{w1, w1} * v23;
      a2a += f32x2{w2, w2} * v01; a2b += f32x2{w2, w2} * v23;
      a3a += f32x2{w3, w3} * v01; a3b += f32x2{w3, w3} * v23;
      hv_c = hv_n;
    }
  }
  if (!alive) return;
  float g[4][4];
  float inv;
  inv = 1.f / (ss01.x + 1e-16f);
  g[0][0] = a0a.x * inv; g[0][1] = a0a.y * inv; g[0][2] = a0b.x * inv; g[0][3] = a0b.y * inv;
  inv = 1.f / (ss01.y + 1e-16f);
  g[1][0] = a1a.x * inv; g[1][1] = a1a.y * inv; g[1][2] = a1b.x * inv; g[1][3] = a1b.y * inv;
  inv = 1.f / (ss23.x + 1e-16f);
  g[2][0] = a2a.x * inv; g[2][1] = a2a.y * inv; g[2][2] = a2b.x * inv; g[2][3] = a2b.y * inv;
  inv = 1.f / (ss23.y + 1e-16f);
  g[3][0] = a3a.x * inv; g[3][1] = a3a.y * inv; g[3][2] = a3b.x * inv; g[3][3] = a3b.y * inv;
#pragma unroll
  for (int h = 0; h < 4; ++h) {
    ushort_t q0 = f_to_f16(g[h][0]), q1 = f_to_f16(g[h][1]);
    ushort_t q2 = f_to_f16(g[h][2]), q3 = f_to_f16(g[h][3]);
    size_t o = ((size_t)(n >> 4) * 64 + h * 16 + (hl >> 1)) * 128 + (n & 15) * 8 + (hl & 1) * 4;
    *(uint2*)&Gf[o] = make_uint2((uint_t)q0 | ((uint_t)q1 << 16),
                                 (uint_t)q2 | ((uint_t)q3 << 16));
  }
}

// ---------------------------------------------------------------------------
// Barrier-lean fp16 MFMA GEMM, K-split 2x. A fragments ALL prefetched upfront
// (one pipelined HBM latency); B (L2-resident) 1-deep prefetched.
// 4 waves/block (2 panels x 2 K-halves). MODE 0: fp16 row out (relu) + fused
// next-layer al; MODE 1: fp16 frag out (relu); MODE 2: fp32 row out (no relu).
// ---------------------------------------------------------------------------
template <int K, int MODE>
__global__ __launch_bounds__(256) void gemm_frag_kernel(
    const ushort_t* __restrict__ Af, const ushort_t* __restrict__ Bf,
    ushort_t* __restrict__ H16, ushort_t* __restrict__ Cf16, float* __restrict__ Cf,
    const float* __restrict__ WsN, const float* __restrict__ WdN,
    float* __restrict__ alS, float* __restrict__ alD,
    int M, const float* __restrict__ bias) {
  constexpr int KT = K >> 5;
  constexpr int KTH = KT >> 1;        // kts per wave (K-split 2x)
  constexpr int PS = 16 * K;          // panel stride (ushorts)
  __shared__ float lacc[2][8][4][64]; // 16 KB, lane-stride 4B: conflict-free
  int lane = threadIdx.x & 63;
  int wv = threadIdx.x >> 6;
  int pair = wv >> 1, khalf = wv & 1;
  int wid = blockIdx.x * 2 + pair;
  int krow = lane >> 4, ml = lane & 15;
  int lb = krow * 128 + ml * 8;
  size_t abase = (size_t)wid * PS + lb + (size_t)khalf * KTH * 512;
  size_t bbase = (size_t)lb + (size_t)khalf * KTH * 512;
  f32x4 acc[8] = {};
  half8 a[KTH];
#pragma unroll
  for (int kt = 0; kt < KTH; ++kt)
    a[kt] = *(const half8*)&Af[abase + kt * 512];
  half8 b_c[8];
#pragma unroll
  for (int j = 0; j < 8; ++j) b_c[j] = *(const half8*)&Bf[j * PS + bbase];
#pragma unroll
  for (int kt = 0; kt < KTH; ++kt) {
    half8 b_n[8];
#pragma unroll
    for (int j = 0; j < 8; ++j)
      b_n[j] = (kt + 1 < KTH) ? *(const half8*)&Bf[j * PS + bbase + (kt + 1) * 512]
                              : b_c[j];
#pragma unroll
    for (int j = 0; j < 8; ++j)
      acc[j] = __builtin_amdgcn_mfma_f32_16x16x32_f16(a[kt], b_c[j], acc[j], 0, 0, 0);
#pragma unroll
    for (int j = 0; j < 8; ++j) b_c[j] = b_n[j];
  }
  if (khalf == 1) {
#pragma unroll
    for (int j = 0; j < 8; ++j)
#pragma unroll
      for (int c = 0; c < 4; ++c) lacc[pair][j][c][lane] = acc[j][c];
  }
  __syncthreads();
  if (khalf == 1) return;
#pragma unroll
  for (int j = 0; j < 8; ++j)
#pragma unroll
    for (int c = 0; c < 4; ++c) acc[j][c] += lacc[pair][j][c][lane];

  int wrow0 = wid * 16;
  if (MODE == 0) {
    float ps[4][4] = {};   // [hh][r]
    float pd[4][4] = {};
#pragma unroll
    for (int j = 0; j < 8; ++j) {
      int col = j * 16 + ml;
      float bv = bias[col];
      float4 w4s = *(const float4*)&WsN[col * 4];
      float4 w4d = *(const float4*)&WdN[col * 4];
#pragma unroll
      for (int r = 0; r < 4; ++r) {
        int row = wrow0 + krow * 4 + r;
        float v = fmaxf(acc[j][r] + bv, 0.f);
        if (row < M) H16[(size_t)row * 128 + col] = f_to_f16(v);
        ps[0][r] += v * w4s.x; ps[1][r] += v * w4s.y;
        ps[2][r] += v * w4s.z; ps[3][r] += v * w4s.w;
        pd[0][r] += v * w4d.x; pd[1][r] += v * w4d.y;
        pd[2][r] += v * w4d.z; pd[3][r] += v * w4d.w;
      }
    }
#pragma unroll
    for (int off = 1; off <= 8; off <<= 1) {
#pragma unroll
      for (int hh = 0; hh < 4; ++hh)
#pragma unroll
        for (int r = 0; r < 4; ++r) {
          ps[hh][r] += __shfl_xor(ps[hh][r], off);
          pd[hh][r] += __shfl_xor(pd[hh][r], off);
        }
    }
    if (ml == 0) {
#pragma unroll
      for (int r = 0; r < 4; ++r) {
        int row = wrow0 + krow * 4 + r;
        if (row < M) {
#pragma unroll
          for (int hh = 0; hh < 4; ++hh) {
            alS[row * 4 + hh] = ps[hh][r];
            alD[row * 4 + hh] = pd[hh][r];
          }
        }
      }
    }
  } else {
#pragma unroll
    for (int j = 0; j < 8; ++j) {
      int col = j * 16 + ml;
      float bv = bias[col];
#pragma unroll
      for (int r = 0; r < 4; ++r) {
        int row = wrow0 + krow * 4 + r;
        if (row < M) {
          float v = acc[j][r] + bv;
          if (MODE != 2) v = fmaxf(v, 0.f);
          if (MODE == 1) {
            size_t o = ((size_t)(row >> 4) * 16 + (col >> 3)) * 128 + (row & 15) * 8 + (col & 7);
            Cf16[o] = f_to_f16(v);
          } else {
            Cf[(size_t)row * 128 + col] = v;
          }
        }
      }
    }
  }
}

// ---------------------------------------------------------------------------
extern "C" void kernel_launch(void* const* d_in, const int* in_sizes, int n_in,
                              void* d_out, int out_size, void* d_ws, size_t ws_size,
                              hipStream_t stream) {
  const float* x  = (const float*)d_in[0];
  const int*   ei = (const int*)d_in[1];
  const float* Wl[3]  = {(const float*)d_in[2], (const float*)d_in[6], (const float*)d_in[10]};
  const float* asr[3] = {(const float*)d_in[3], (const float*)d_in[7], (const float*)d_in[11]};
  const float* adr[3] = {(const float*)d_in[4], (const float*)d_in[8], (const float*)d_in[12]};
  const float* bl[3]  = {(const float*)d_in[5], (const float*)d_in[9], (const float*)d_in[13]};
  const float* Wp = (const float*)d_in[14];
  const float* bp = (const float*)d_in[15];

  const int N = in_sizes[0] / 128;   // 50000
  const int E = in_sizes[1] / 2;     // 400000
  const int EN = E + N;
  const int Mtiles = (N + 127) / 128;  // 391
  const int Mp = Mtiles * 128;         // 50048
  const int NB = (N + 255) / 256;
  const int NPB2 = Mp / 16 / 2;        // 1564 GEMM blocks (2 panels x 2 waves)

  char* ws = (char*)d_ws;
  size_t off = 0;
  auto carve = [&](size_t bytes) -> void* {
    void* p = ws + off;
    off = (off + bytes + 255) & ~(size_t)255;
    return p;
  };
  ushort_t* Gf    = (ushort_t*)carve((size_t)Mp * 512 * 2);  // fp16 frag layout
  ushort_t* h16   = (ushort_t*)carve((size_t)N * 128 * 2);   // fp16 h (agg gather)
  ushort_t* h3f   = (ushort_t*)carve((size_t)Mp * 128 * 2);  // fp16 frag (proj input)
  ushort_t* wsf0  = (ushort_t*)carve((size_t)128 * 512 * 2);
  ushort_t* wsf1  = (ushort_t*)carve((size_t)128 * 512 * 2);
  ushort_t* wsf2  = (ushort_t*)carve((size_t)128 * 512 * 2);
  ushort_t* wpf   = (ushort_t*)carve((size_t)128 * 128 * 2);
  float*    alsrc = (float*)carve((size_t)N * 4 * 4);
  float*    aldst = (float*)carve((size_t)N * 4 * 4);
  float*    Ws4   = (float*)carve(3 * 512 * 4);
  float*    Wd4   = (float*)carve(3 * 512 * 4);
  float*    Wsh   = (float*)carve(3 * 512 * 4);
  float*    Wdh   = (float*)carve(3 * 512 * 4);
  int*      rowptr= (int*)carve((size_t)(N + 1) * 4);
  int*      deg   = (int*)carve((size_t)N * 4);
  int*      bsum  = (int*)carve(256 * 4);
  int*      fillc = (int*)carve((size_t)N * 4);
  int*      colbuf= (int*)carve((size_t)EN * 4);
  int*      flag  = (int*)carve(256);

  // ---- CSR build ----
  detect_i64_kernel<<<1, 64, 0, stream>>>(ei, flag);
  hipMemsetAsync(deg, 0, (size_t)N * 4, stream);
  hipMemsetAsync(fillc, 0, (size_t)N * 4, stream);
  int ebl = (EN + 255) / 256;
  deg_kernel<<<ebl, 256, 0, stream>>>(ei, flag, E, N, deg);
  scan_blk_kernel<<<NB, 256, 0, stream>>>(deg, rowptr, bsum, N);
  scan_top_kernel<<<1, 256, 0, stream>>>(bsum, NB);
  scan_add_kernel<<<NB, 256, 0, stream>>>(rowptr, bsum, N);
  fill_kernel<<<ebl, 256, 0, stream>>>(ei, flag, E, N, rowptr, fillc, colbuf);

  // ---- weight prep; single x pass (h16 + layer-0 al) ----
  prep_weights_kernel<<<832, 256, 0, stream>>>(Wl[0], Wl[1], Wl[2], Wp,
                                               wsf0, wsf1, wsf2, wpf);
  wsd_all_kernel<<<96, 256, 0, stream>>>(Wl[0], Wl[1], Wl[2],
                                         asr[0], asr[1], asr[2],
                                         adr[0], adr[1], adr[2],
                                         Ws4, Wd4, Wsh, Wdh);
  x_prep_kernel<<<(N + 3) / 4, 256, 0, stream>>>(x, Wsh, Wdh, h16, alsrc, aldst, N);

  // ---- 3 GAT layers ----
  ushort_t* wsfL[3] = {wsf0, wsf1, wsf2};
  for (int L = 0; L < 3; ++L) {
    agg_G_kernel<<<Mp / 8, 256, 0, stream>>>(h16, alsrc, aldst,
                                             rowptr, colbuf, Gf, N);
    if (L < 2) {
      gemm_frag_kernel<512, 0><<<NPB2, 256, 0, stream>>>(Gf, wsfL[L],
                                                         h16, nullptr, nullptr,
                                                         Ws4 + (L + 1) * 512, Wd4 + (L + 1) * 512,
                                                         alsrc, aldst, N, bl[L]);
    } else {
      gemm_frag_kernel<512, 1><<<NPB2, 256, 0, stream>>>(Gf, wsfL[L],
                                                         nullptr, h3f, nullptr,
                                                         nullptr, nullptr, nullptr, nullptr,
                                                         N, bl[L]);
    }
  }

  // ---- final projection: out = h3 @ Wp + bp ----
  gemm_frag_kernel<128, 2><<<NPB2, 256, 0, stream>>>(h3f, wpf,
                                                     nullptr, nullptr, (float*)d_out,
                                                     nullptr, nullptr, nullptr, nullptr,
                                                     N, bp);
}

// Round 22
// 299.138 us; speedup vs baseline: 1.0647x; 1.0186x over previous
//
#include <hip/hip_runtime.h>
#include <cstddef>
#include <cstdint>

typedef _Float16 half8 __attribute__((ext_vector_type(8)));
typedef float f32x4 __attribute__((ext_vector_type(4)));
typedef float f32x2 __attribute__((ext_vector_type(2)));
typedef unsigned short ushort_t;
typedef unsigned int uint_t;
typedef ushort_t ushort4v __attribute__((ext_vector_type(4)));
typedef float f32x4v __attribute__((ext_vector_type(4)));

#define INV_LN2 1.4426950408889634f

__device__ __forceinline__ ushort_t f_to_f16(float f) {
  _Float16 h = (_Float16)f;
  union { _Float16 h; ushort_t u; } v; v.h = h; return v.u;
}
__device__ __forceinline__ float f16_to_f(ushort_t u) {
  union { ushort_t u; _Float16 h; } v; v.u = u; return (float)v.h;
}

// ---------------------------------------------------------------------------
// CSR build
// ---------------------------------------------------------------------------
__global__ __launch_bounds__(64) void detect_i64_kernel(const int* __restrict__ ei,
                                                        int* __restrict__ flag) {
  if (threadIdx.x == 0) {
    int is32 = 0;
    for (int i = 1; i < 1001; i += 2) {
      if (ei[i] != 0) { is32 = 1; break; }
    }
    *flag = is32;
  }
}

__device__ __forceinline__ int load_src(const int* ei, int is32, int E, int e) {
  return is32 ? ei[e] : ei[2 * e];
}
__device__ __forceinline__ int load_dst(const int* ei, int is32, int E, int e) {
  return is32 ? ei[E + e] : ei[2 * (E + e)];
}

__global__ __launch_bounds__(256) void deg_kernel(const int* __restrict__ ei,
                                                  const int* __restrict__ flag,
                                                  int E, int N, int* __restrict__ deg) {
  int e = blockIdx.x * 256 + threadIdx.x;
  if (e >= E + N) return;
  int d = (e < E) ? load_dst(ei, *flag, E, e) : (e - E);
  atomicAdd(&deg[d], 1);
}

__global__ __launch_bounds__(256) void scan_blk_kernel(const int* __restrict__ deg,
                                                       int* __restrict__ rowptr,
                                                       int* __restrict__ bsum, int N) {
  __shared__ int buf[256];
  int b = blockIdx.x, t = threadIdx.x, i = b * 256 + t;
  int v = (i < N) ? deg[i] : 0;
  buf[t] = v;
  __syncthreads();
  for (int off = 1; off < 256; off <<= 1) {
    int add = (t >= off) ? buf[t - off] : 0;
    __syncthreads();
    buf[t] += add;
    __syncthreads();
  }
  if (i < N) rowptr[i + 1] = buf[t];
  if (t == 255) bsum[b] = buf[255];
  if (b == 0 && t == 0) rowptr[0] = 0;
}

// scan_add2: each block computes its own prefix over raw block totals
// (bsum[0..b-1]) and adds it to its rowptr entries. Replaces scan_top+scan_add.
__global__ __launch_bounds__(256) void scan_add2_kernel(int* __restrict__ rowptr,
                                                        const int* __restrict__ bsum,
                                                        int N) {
  __shared__ int buf[256];
  int b = blockIdx.x, t = threadIdx.x;
  int s = 0;
  for (int i = t; i < b; i += 256) s += bsum[i];
  buf[t] = s;
  __syncthreads();
  for (int off = 128; off; off >>= 1) {
    if (t < off) buf[t] += buf[t + off];
    __syncthreads();
  }
  int base = buf[0];
  int i = b * 256 + t;
  if (b > 0 && i < N) rowptr[i + 1] += base;
}

__global__ __launch_bounds__(256) void fill_kernel(const int* __restrict__ ei,
                                                   const int* __restrict__ flag,
                                                   int E, int N,
                                                   const int* __restrict__ rowptr,
                                                   int* __restrict__ fillc,
                                                   int* __restrict__ colbuf) {
  int e = blockIdx.x * 256 + threadIdx.x;
  if (e >= E + N) return;
  int s, d;
  if (e < E) { int is32 = *flag; s = load_src(ei, is32, E, e); d = load_dst(ei, is32, E, e); }
  else { s = e - E; d = s; }
  int pos = atomicAdd(&fillc[d], 1);
  colbuf[rowptr[d] + pos] = s;
}

// ---------------------------------------------------------------------------
// prep: single kernel for all weight transforms.
// blocks [0,768): Wstack fp16 frags (3 layers); [768,832): Wp frag;
// [832,928): folded attention vectors (wsd, both layouts).
// ---------------------------------------------------------------------------
__global__ __launch_bounds__(256) void prep_all_kernel(
    const float* __restrict__ W0, const float* __restrict__ W1,
    const float* __restrict__ W2, const float* __restrict__ Wp,
    const float* __restrict__ as0, const float* __restrict__ as1,
    const float* __restrict__ as2,
    const float* __restrict__ ad0, const float* __restrict__ ad1,
    const float* __restrict__ ad2,
    ushort_t* __restrict__ wsf0, ushort_t* __restrict__ wsf1,
    ushort_t* __restrict__ wsf2, ushort_t* __restrict__ wpf,
    float* __restrict__ Ws4, float* __restrict__ Wd4,
    float* __restrict__ Wsh, float* __restrict__ Wdh) {
  int b = blockIdx.x;
  if (b < 768) {
    int L = b >> 8;
    const float* W = (L == 0) ? W0 : (L == 1) ? W1 : W2;
    ushort_t* out = (L == 0) ? wsf0 : (L == 1) ? wsf1 : wsf2;
    int t = (b & 255) * 256 + threadIdx.x;   // 0..65535
    int c16 = t >> 13;
    int r = t & 8191;
    int k8 = r >> 7;
    int rem = r & 127;
    int rl = rem >> 3, kl = rem & 7;
    int col = c16 * 16 + rl;
    int k = k8 * 8 + kl;
    int h = k >> 7, f = k & 127;
    out[t] = f_to_f16(0.25f * W[(size_t)f * 512 + h * 128 + col]);
  } else if (b < 832) {
    int t = (b - 768) * 256 + threadIdx.x;   // 0..16383
    int blk = t >> 7, rem = t & 127;
    int c16 = blk >> 4, k8 = blk & 15;
    int cl = rem >> 3, kl = rem & 7;
    int col = c16 * 16 + cl, k = k8 * 8 + kl;
    wpf[t] = f_to_f16(Wp[(size_t)k * 128 + col]);
  } else {
    int bb = b - 832;                        // 0..95
    int L = bb >> 5;
    const float* W = (L == 0) ? W0 : (L == 1) ? W1 : W2;
    const float* a_src = (L == 0) ? as0 : (L == 1) ? as1 : as2;
    const float* a_dst = (L == 0) ? ad0 : (L == 1) ? ad1 : ad2;
    int wave = threadIdx.x >> 6, lane = threadIdx.x & 63;
    int f = (bb & 31) * 4 + wave;            // f in [0,128)
    int base = lane * 8;
    float4 w0 = *(const float4*)&W[(size_t)f * 512 + base];
    float4 w1 = *(const float4*)&W[(size_t)f * 512 + base + 4];
    float4 s0 = *(const float4*)&a_src[base];
    float4 s1 = *(const float4*)&a_src[base + 4];
    float4 d0 = *(const float4*)&a_dst[base];
    float4 d1 = *(const float4*)&a_dst[base + 4];
    float ps = w0.x*s0.x + w0.y*s0.y + w0.z*s0.z + w0.w*s0.w
             + w1.x*s1.x + w1.y*s1.y + w1.z*s1.z + w1.w*s1.w;
    float pd = w0.x*d0.x + w0.y*d0.y + w0.z*d0.z + w0.w*d0.w
             + w1.x*d1.x + w1.y*d1.y + w1.z*d1.z + w1.w*d1.w;
#pragma unroll
    for (int off = 1; off <= 8; off <<= 1) {
      ps += __shfl_xor(ps, off);
      pd += __shfl_xor(pd, off);
    }
    if ((lane & 15) == 0) {
      int h = lane >> 4;
      float vs = ps * INV_LN2, vd = pd * INV_LN2;
      Ws4[L * 512 + f * 4 + h] = vs;
      Wd4[L * 512 + f * 4 + h] = vd;
      Wsh[L * 512 + h * 128 + f] = vs;
      Wdh[L * 512 + h * 128 + f] = vd;
    }
  }
}

// x prep: single pass over x computes h16 (fp16) AND layer-0 al.
// One wave per node; Ws/Wd in [h][128] layout.
__global__ __launch_bounds__(256) void x_prep_kernel(const float* __restrict__ x,
                                                     const float* __restrict__ Wsh,
                                                     const float* __restrict__ Wdh,
                                                     ushort_t* __restrict__ h16,
                                                     float* __restrict__ al_src,
                                                     float* __restrict__ al_dst, int N) {
  __shared__ float sWs[512], sWd[512];
  int t = threadIdx.x;
  sWs[t] = Wsh[t]; sWs[t + 256] = Wsh[t + 256];
  sWd[t] = Wdh[t]; sWd[t + 256] = Wdh[t + 256];
  __syncthreads();
  int wave = t >> 6, lane = t & 63;
  int n = blockIdx.x * 4 + wave;
  if (n >= N) return;
  float2 hv = *(const float2*)&x[(size_t)n * 128 + lane * 2];
  uint_t pk = (uint_t)f_to_f16(hv.x) | ((uint_t)f_to_f16(hv.y) << 16);
  *(uint_t*)&h16[(size_t)n * 128 + lane * 2] = pk;
  float p[8];
#pragma unroll
  for (int hh = 0; hh < 4; ++hh) {
    p[hh]     = hv.x * sWs[hh * 128 + 2 * lane] + hv.y * sWs[hh * 128 + 2 * lane + 1];
    p[4 + hh] = hv.x * sWd[hh * 128 + 2 * lane] + hv.y * sWd[hh * 128 + 2 * lane + 1];
  }
#pragma unroll
  for (int off = 32; off; off >>= 1)
#pragma unroll
    for (int i = 0; i < 8; ++i) p[i] += __shfl_xor(p[i], off);
  if (lane == 0) {
#pragma unroll
    for (int hh = 0; hh < 4; ++hh) {
      al_src[n * 4 + hh] = p[hh];
      al_dst[n * 4 + hh] = p[4 + hh];
    }
  }
}

// ---------------------------------------------------------------------------
// aggregation v3: 2 nodes/wave, chunks of 8 edges, quad-specialized logits,
// chunk-granularity rescale, shuffled weight broadcast, fp16 gather.
// fp16 frag output.
// ---------------------------------------------------------------------------
__global__ __launch_bounds__(256) void agg_G_kernel(const ushort_t* __restrict__ h16,
                                                    const float* __restrict__ al_src,
                                                    const float* __restrict__ al_dst,
                                                    const int* __restrict__ rowptr,
                                                    const int* __restrict__ colbuf,
                                                    ushort_t* __restrict__ Gf, int N) {
  int wave = threadIdx.x >> 6, lane = threadIdx.x & 63;
  int hl = lane & 31;
  int half_base = lane & 32;
  int q = hl >> 2, hc = hl & 3;
  int qb = lane & ~3;
  int n = blockIdx.x * 8 + wave * 2 + (lane >> 5);
  bool alive = n < N;
  int beg = 0, d = 0;
  float ald_hc = 0.f;
  if (alive) {
    beg = rowptr[n];
    d = rowptr[n + 1] - beg;
    ald_hc = al_dst[(size_t)n * 4 + hc];
  }
  int dm1 = max(d - 1, 0);
  float m_run = -1e30f;
  f32x2 ss01 = {0.f, 0.f}, ss23 = {0.f, 0.f};
  f32x2 a0a = {0.f,0.f}, a0b = {0.f,0.f};
  f32x2 a1a = {0.f,0.f}, a1b = {0.f,0.f};
  f32x2 a2a = {0.f,0.f}, a2b = {0.f,0.f};
  f32x2 a3a = {0.f,0.f}, a3b = {0.f,0.f};

  for (int c0 = 0; c0 < d; c0 += 8) {
    int cn = min(8, d - c0);
    int j = c0 + q;
    int sq = colbuf[beg + min(j, dm1)];
    float e = al_src[(size_t)sq * 4 + hc] + ald_hc;
    e = fmaxf(e, 0.2f * e);
    e = (q < cn) ? e : -1e30f;
    float mc = e;
    mc = fmaxf(mc, __shfl_xor(mc, 4));
    mc = fmaxf(mc, __shfl_xor(mc, 8));
    mc = fmaxf(mc, __shfl_xor(mc, 16));
    float nm = fmaxf(m_run, mc);
    float fown = exp2f(m_run - nm);
    m_run = nm;
    float w_own = (q < cn) ? exp2f(e - nm) : 0.f;
    float f0 = __shfl(fown, qb + 0), f1 = __shfl(fown, qb + 1);
    float f2 = __shfl(fown, qb + 2), f3 = __shfl(fown, qb + 3);
    ss01 *= f32x2{f0, f1}; ss23 *= f32x2{f2, f3};
    f32x2 F0 = {f0, f0}, F1 = {f1, f1}, F2 = {f2, f2}, F3 = {f3, f3};
    a0a *= F0; a0b *= F0; a1a *= F1; a1b *= F1;
    a2a *= F2; a2b *= F2; a3a *= F3; a3b *= F3;
    int s_c = __shfl(sq, half_base);
    ushort4v hv_c = *(const ushort4v*)&h16[(size_t)s_c * 128 + hl * 4];
    for (int jj = 0; jj < cn; ++jj) {
      int s_n = __shfl(sq, half_base + min(jj + 1, cn - 1) * 4);
      ushort4v hv_n = *(const ushort4v*)&h16[(size_t)s_n * 128 + hl * 4];
      int wb = half_base + jj * 4;
      float w0 = __shfl(w_own, wb + 0);
      float w1 = __shfl(w_own, wb + 1);
      float w2 = __shfl(w_own, wb + 2);
      float w3 = __shfl(w_own, wb + 3);
      ss01 += f32x2{w0, w1}; ss23 += f32x2{w2, w3};
      f32x2 v01 = {f16_to_f(hv_c[0]), f16_to_f(hv_c[1])};
      f32x2 v23 = {f16_to_f(hv_c[2]), f16_to_f(hv_c[3])};
      a0a += f32x2{w0, w0} * v01; a0b += f32x2{w0, w0} * v23;
      a1a += f32x2{w1, w1} * v01; a1b += f32x2{w1, w1} * v23;
      a2a += f32x2{w2, w2} * v01; a2b += f32x2{w2, w2} * v23;
      a3a += f32x2{w3, w3} * v01; a3b += f32x2{w3, w3} * v23;
      hv_c = hv_n;
    }
  }
  if (!alive) return;
  float g[4][4];
  float inv;
  inv = 1.f / (ss01.x + 1e-16f);
  g[0][0] = a0a.x * inv; g[0][1] = a0a.y * inv; g[0][2] = a0b.x * inv; g[0][3] = a0b.y * inv;
  inv = 1.f / (ss01.y + 1e-16f);
  g[1][0] = a1a.x * inv; g[1][1] = a1a.y * inv; g[1][2] = a1b.x * inv; g[1][3] = a1b.y * inv;
  inv = 1.f / (ss23.x + 1e-16f);
  g[2][0] = a2a.x * inv; g[2][1] = a2a.y * inv; g[2][2] = a2b.x * inv; g[2][3] = a2b.y * inv;
  inv = 1.f / (ss23.y + 1e-16f);
  g[3][0] = a3a.x * inv; g[3][1] = a3a.y * inv; g[3][2] = a3b.x * inv; g[3][3] = a3b.y * inv;
#pragma unroll
  for (int h = 0; h < 4; ++h) {
    ushort_t q0 = f_to_f16(g[h][0]), q1 = f_to_f16(g[h][1]);
    ushort_t q2 = f_to_f16(g[h][2]), q3 = f_to_f16(g[h][3]);
    size_t o = ((size_t)(n >> 4) * 64 + h * 16 + (hl >> 1)) * 128 + (n & 15) * 8 + (hl & 1) * 4;
    *(uint2*)&Gf[o] = make_uint2((uint_t)q0 | ((uint_t)q1 << 16),
                                 (uint_t)q2 | ((uint_t)q3 << 16));
  }
}

// ---------------------------------------------------------------------------
// Barrier-lean fp16 MFMA GEMM, K-split 2x. A fragments ALL prefetched upfront
// (one pipelined HBM latency); B (L2-resident) 1-deep prefetched.
// 4 waves/block (2 panels x 2 K-halves). MODE 0: fp16 row out (relu) + fused
// next-layer al; MODE 1: fp16 frag out (relu); MODE 2: fp32 row out (no relu).
// ---------------------------------------------------------------------------
template <int K, int MODE>
__global__ __launch_bounds__(256) void gemm_frag_kernel(
    const ushort_t* __restrict__ Af, const ushort_t* __restrict__ Bf,
    ushort_t* __restrict__ H16, ushort_t* __restrict__ Cf16, float* __restrict__ Cf,
    const float* __restrict__ WsN, const float* __restrict__ WdN,
    float* __restrict__ alS, float* __restrict__ alD,
    int M, const float* __restrict__ bias) {
  constexpr int KT = K >> 5;
  constexpr int KTH = KT >> 1;        // kts per wave (K-split 2x)
  constexpr int PS = 16 * K;          // panel stride (ushorts)
  __shared__ float lacc[2][8][4][64]; // 16 KB, lane-stride 4B: conflict-free
  int lane = threadIdx.x & 63;
  int wv = threadIdx.x >> 6;
  int pair = wv >> 1, khalf = wv & 1;
  int wid = blockIdx.x * 2 + pair;
  int krow = lane >> 4, ml = lane & 15;
  int lb = krow * 128 + ml * 8;
  size_t abase = (size_t)wid * PS + lb + (size_t)khalf * KTH * 512;
  size_t bbase = (size_t)lb + (size_t)khalf * KTH * 512;
  f32x4 acc[8] = {};
  half8 a[KTH];
#pragma unroll
  for (int kt = 0; kt < KTH; ++kt)
    a[kt] = *(const half8*)&Af[abase + kt * 512];
  half8 b_c[8];
#pragma unroll
  for (int j = 0; j < 8; ++j) b_c[j] = *(const half8*)&Bf[j * PS + bbase];
#pragma unroll
  for (int kt = 0; kt < KTH; ++kt) {
    half8 b_n[8];
#pragma unroll
    for (int j = 0; j < 8; ++j)
      b_n[j] = (kt + 1 < KTH) ? *(const half8*)&Bf[j * PS + bbase + (kt + 1) * 512]
                              : b_c[j];
#pragma unroll
    for (int j = 0; j < 8; ++j)
      acc[j] = __builtin_amdgcn_mfma_f32_16x16x32_f16(a[kt], b_c[j], acc[j], 0, 0, 0);
#pragma unroll
    for (int j = 0; j < 8; ++j) b_c[j] = b_n[j];
  }
  if (khalf == 1) {
#pragma unroll
    for (int j = 0; j < 8; ++j)
#pragma unroll
      for (int c = 0; c < 4; ++c) lacc[pair][j][c][lane] = acc[j][c];
  }
  __syncthreads();
  if (khalf == 1) return;
#pragma unroll
  for (int j = 0; j < 8; ++j)
#pragma unroll
    for (int c = 0; c < 4; ++c) acc[j][c] += lacc[pair][j][c][lane];

  int wrow0 = wid * 16;
  if (MODE == 0) {
    float ps[4][4] = {};   // [hh][r]
    float pd[4][4] = {};
#pragma unroll
    for (int j = 0; j < 8; ++j) {
      int col = j * 16 + ml;
      float bv = bias[col];
      float4 w4s = *(const float4*)&WsN[col * 4];
      float4 w4d = *(const float4*)&WdN[col * 4];
#pragma unroll
      for (int r = 0; r < 4; ++r) {
        int row = wrow0 + krow * 4 + r;
        float v = fmaxf(acc[j][r] + bv, 0.f);
        if (row < M) H16[(size_t)row * 128 + col] = f_to_f16(v);
        ps[0][r] += v * w4s.x; ps[1][r] += v * w4s.y;
        ps[2][r] += v * w4s.z; ps[3][r] += v * w4s.w;
        pd[0][r] += v * w4d.x; pd[1][r] += v * w4d.y;
        pd[2][r] += v * w4d.z; pd[3][r] += v * w4d.w;
      }
    }
#pragma unroll
    for (int off = 1; off <= 8; off <<= 1) {
#pragma unroll
      for (int hh = 0; hh < 4; ++hh)
#pragma unroll
        for (int r = 0; r < 4; ++r) {
          ps[hh][r] += __shfl_xor(ps[hh][r], off);
          pd[hh][r] += __shfl_xor(pd[hh][r], off);
        }
    }
    if (ml == 0) {
#pragma unroll
      for (int r = 0; r < 4; ++r) {
        int row = wrow0 + krow * 4 + r;
        if (row < M) {
#pragma unroll
          for (int hh = 0; hh < 4; ++hh) {
            alS[row * 4 + hh] = ps[hh][r];
            alD[row * 4 + hh] = pd[hh][r];
          }
        }
      }
    }
  } else {
#pragma unroll
    for (int j = 0; j < 8; ++j) {
      int col = j * 16 + ml;
      float bv = bias[col];
#pragma unroll
      for (int r = 0; r < 4; ++r) {
        int row = wrow0 + krow * 4 + r;
        if (row < M) {
          float v = acc[j][r] + bv;
          if (MODE != 2) v = fmaxf(v, 0.f);
          if (MODE == 1) {
            size_t o = ((size_t)(row >> 4) * 16 + (col >> 3)) * 128 + (row & 15) * 8 + (col & 7);
            Cf16[o] = f_to_f16(v);
          } else {
            Cf[(size_t)row * 128 + col] = v;
          }
        }
      }
    }
  }
}

// ---------------------------------------------------------------------------
extern "C" void kernel_launch(void* const* d_in, const int* in_sizes, int n_in,
                              void* d_out, int out_size, void* d_ws, size_t ws_size,
                              hipStream_t stream) {
  const float* x  = (const float*)d_in[0];
  const int*   ei = (const int*)d_in[1];
  const float* Wl[3]  = {(const float*)d_in[2], (const float*)d_in[6], (const float*)d_in[10]};
  const float* asr[3] = {(const float*)d_in[3], (const float*)d_in[7], (const float*)d_in[11]};
  const float* adr[3] = {(const float*)d_in[4], (const float*)d_in[8], (const float*)d_in[12]};
  const float* bl[3]  = {(const float*)d_in[5], (const float*)d_in[9], (const float*)d_in[13]};
  const float* Wp = (const float*)d_in[14];
  const float* bp = (const float*)d_in[15];

  const int N = in_sizes[0] / 128;   // 50000
  const int E = in_sizes[1] / 2;     // 400000
  const int EN = E + N;
  const int Mtiles = (N + 127) / 128;  // 391
  const int Mp = Mtiles * 128;         // 50048
  const int NB = (N + 255) / 256;
  const int NPB2 = Mp / 16 / 2;        // 1564 GEMM blocks (2 panels x 2 waves)

  char* ws = (char*)d_ws;
  size_t off = 0;
  auto carve = [&](size_t bytes) -> void* {
    void* p = ws + off;
    off = (off + bytes + 255) & ~(size_t)255;
    return p;
  };
  ushort_t* Gf    = (ushort_t*)carve((size_t)Mp * 512 * 2);  // fp16 frag layout
  ushort_t* h16   = (ushort_t*)carve((size_t)N * 128 * 2);   // fp16 h (agg gather)
  ushort_t* h3f   = (ushort_t*)carve((size_t)Mp * 128 * 2);  // fp16 frag (proj input)
  ushort_t* wsf0  = (ushort_t*)carve((size_t)128 * 512 * 2);
  ushort_t* wsf1  = (ushort_t*)carve((size_t)128 * 512 * 2);
  ushort_t* wsf2  = (ushort_t*)carve((size_t)128 * 512 * 2);
  ushort_t* wpf   = (ushort_t*)carve((size_t)128 * 128 * 2);
  float*    alsrc = (float*)carve((size_t)N * 4 * 4);
  float*    aldst = (float*)carve((size_t)N * 4 * 4);
  float*    Ws4   = (float*)carve(3 * 512 * 4);
  float*    Wd4   = (float*)carve(3 * 512 * 4);
  float*    Wsh   = (float*)carve(3 * 512 * 4);
  float*    Wdh   = (float*)carve(3 * 512 * 4);
  int*      rowptr= (int*)carve((size_t)(N + 1) * 4);
  int*      deg   = (int*)carve((size_t)N * 4);   // deg+fillc adjacent: one memset
  int*      fillc = (int*)carve((size_t)N * 4);
  int*      bsum  = (int*)carve(256 * 4);
  int*      colbuf= (int*)carve((size_t)EN * 4);
  int*      flag  = (int*)carve(256);

  // ---- CSR build ----
  detect_i64_kernel<<<1, 64, 0, stream>>>(ei, flag);
  size_t zbytes = (size_t)((char*)fillc - (char*)deg) + (size_t)N * 4;
  hipMemsetAsync(deg, 0, zbytes, stream);   // zeroes deg AND fillc in one call
  int ebl = (EN + 255) / 256;
  deg_kernel<<<ebl, 256, 0, stream>>>(ei, flag, E, N, deg);
  scan_blk_kernel<<<NB, 256, 0, stream>>>(deg, rowptr, bsum, N);
  scan_add2_kernel<<<NB, 256, 0, stream>>>(rowptr, bsum, N);
  fill_kernel<<<ebl, 256, 0, stream>>>(ei, flag, E, N, rowptr, fillc, colbuf);

  // ---- all weight prep in one launch; single x pass (h16 + layer-0 al) ----
  prep_all_kernel<<<928, 256, 0, stream>>>(Wl[0], Wl[1], Wl[2], Wp,
                                           asr[0], asr[1], asr[2],
                                           adr[0], adr[1], adr[2],
                                           wsf0, wsf1, wsf2, wpf,
                                           Ws4, Wd4, Wsh, Wdh);
  x_prep_kernel<<<(N + 3) / 4, 256, 0, stream>>>(x, Wsh, Wdh, h16, alsrc, aldst, N);

  // ---- 3 GAT layers ----
  ushort_t* wsfL[3] = {wsf0, wsf1, wsf2};
  for (int L = 0; L < 3; ++L) {
    agg_G_kernel<<<Mp / 8, 256, 0, stream>>>(h16, alsrc, aldst,
                                             rowptr, colbuf, Gf, N);
    if (L < 2) {
      gemm_frag_kernel<512, 0><<<NPB2, 256, 0, stream>>>(Gf, wsfL[L],
                                                         h16, nullptr, nullptr,
                                                         Ws4 + (L + 1) * 512, Wd4 + (L + 1) * 512,
                                                         alsrc, aldst, N, bl[L]);
    } else {
      gemm_frag_kernel<512, 1><<<NPB2, 256, 0, stream>>>(Gf, wsfL[L],
                                                         nullptr, h3f, nullptr,
                                                         nullptr, nullptr, nullptr, nullptr,
                                                         N, bl[L]);
    }
  }

  // ---- final projection: out = h3 @ Wp + bp ----
  gemm_frag_kernel<128, 2><<<NPB2, 256, 0, stream>>>(h3f, wpf,
                                                     nullptr, nullptr, (float*)d_out,
                                                     nullptr, nullptr, nullptr, nullptr,
                                                     N, bp);
}